// Round 12
// baseline (1283.033 us; speedup 1.0000x reference)
//
#include <hip/hip_runtime.h>
#include <stdint.h>

#define T_ 512
#define K_ 256
#define NB 16
#define WROW 264   // bf16 W row stride in ushorts
#define WSTR 272   // fp8 W row stride in bytes (MX probe)
#define L2E 1.4426950408889634f
#define LN2 0.6931471805599453f

typedef __attribute__((ext_vector_type(8))) short short8;
typedef __attribute__((ext_vector_type(4))) float f32x4;
typedef __attribute__((ext_vector_type(8))) int int8v;

__device__ __forceinline__ float fexp2(float x) {
#if __has_builtin(__builtin_amdgcn_exp2f)
  return __builtin_amdgcn_exp2f(x);
#else
  return exp2f(x);
#endif
}
__device__ __forceinline__ float flog2(float x) {
#if __has_builtin(__builtin_amdgcn_logf)
  return __builtin_amdgcn_logf(x);
#else
  return log2f(x);
#endif
}
__device__ __forceinline__ unsigned int umax_(unsigned int a, unsigned int b) {
  return a > b ? a : b;
}
__device__ __forceinline__ float bits2f(uint32_t u) { return __builtin_bit_cast(float, u); }
__device__ __forceinline__ uint32_t f2bits(float f) { return __builtin_bit_cast(uint32_t, f); }

__device__ __forceinline__ unsigned short f2bf(float f) {
  union { float f; uint32_t u; } v; v.f = f;
  uint32_t r = v.u + 0x7fffu + ((v.u >> 16) & 1u);
  return (unsigned short)(r >> 16);
}
__device__ __forceinline__ uint32_t cvt_pk_bf16(float a, float b) {
  uint32_t d;
  asm("v_cvt_pk_bf16_f32 %0, %1, %2" : "=v"(d) : "v"(a), "v"(b));
  return d;
}
__device__ unsigned char to_e4m3(float f) {
  if (!(f > 0.0f)) return 0;
  if (f >= 448.0f) return 0x7E;
  uint32_t u = f2bits(f);
  int e = (int)((u >> 23) & 255) - 127;
  uint32_t m = u & 0x7fffff;
  if (e < -6) {
    int s2 = 20 + (-6 - e);
    if (s2 >= 24) return 0;
    uint32_t full = 0x800000u | m;
    uint32_t q = full >> s2, r = full & ((1u << s2) - 1);
    uint32_t half = 1u << (s2 - 1);
    q += (r > half || (r == half && (q & 1))) ? 1u : 0u;
    return (unsigned char)q;
  }
  uint32_t q = m >> 20, r = m & 0xFFFFFu;
  q += (r > 0x80000u || (r == 0x80000u && (q & 1))) ? 1u : 0u;
  if (q == 8) { q = 0; e += 1; if (e > 8) return 0x7E; }
  return (unsigned char)(((e + 7) << 3) | q);
}
template<bool HI>
__device__ __forceinline__ uint32_t pk_fp8(float a, float b, uint32_t old) {
#if __has_builtin(__builtin_amdgcn_cvt_pk_fp8_f32)
  return (uint32_t)__builtin_amdgcn_cvt_pk_fp8_f32(a, b, (int)old, HI);
#else
  uint32_t v = (uint32_t)to_e4m3(a) | ((uint32_t)to_e4m3(b) << 8);
  return HI ? ((old & 0x0000FFFFu) | (v << 16)) : ((old & 0xFFFF0000u) | v);
#endif
}

#define BAR() do { \
  asm volatile("s_waitcnt lgkmcnt(0)" ::: "memory"); \
  __builtin_amdgcn_s_barrier(); \
  asm volatile("" ::: "memory"); \
} while (0)

// ---------- aux kernels ----------

// bf16 A-frags for 16x16x32 (r6-proven layout)
__global__ void prep_E_bf(const float* __restrict__ trans, unsigned short* __restrict__ Efrag) {
  int idx = blockIdx.x * 256 + threadIdx.x;
  int e = idx & 7;
  int ln = (idx >> 3) & 63;
  int kb = (idx >> 9) & 7;
  int mt = idx >> 12;
  int j = mt * 16 + (ln & 15);
  int k = kb * 32 + ((ln >> 4) << 3) + e;
  Efrag[idx] = f2bf(__expf(trans[k * K_ + j]));
}

// e4m3 A-frags for mfma_scale 16x16x128 (r11 layout, timing probe only)
__global__ void prep_E_mx(const float* __restrict__ trans, unsigned char* __restrict__ Efrag) {
  int idx = blockIdx.x * 256 + threadIdx.x;
  int e = idx & 31;
  int ln = (idx >> 5) & 63;
  int h = (idx >> 11) & 1;
  int tile = idx >> 12;
  int j = tile * 16 + (ln & 15);
  int k = h * 128 + ((ln >> 4) << 5) + e;
  Efrag[idx] = to_e4m3(__expf(trans[k * K_ + j]));
}

__global__ void aux_mask(const float* __restrict__ yp, unsigned char* __restrict__ masks) {
  int item = blockIdx.x * 4 + (threadIdx.x >> 6);
  int lane = threadIdx.x & 63;
  const float4 v = *(const float4*)(yp + (size_t)item * K_ + lane * 4);
  float mn = fminf(fminf(v.x, v.y), fminf(v.z, v.w));
  unsigned long long bl = __ballot(mn > -1000000.0f);
  if (lane == 0) {
    int b = item >> 9, t = item & 511;
    masks[t * 128 + b] = (bl == ~0ull) ? 1 : 0;
  }
}

__global__ void aux_score(const float* __restrict__ yp, const float* __restrict__ trans,
                          const int* __restrict__ ytrue, const unsigned char* __restrict__ masks,
                          float* __restrict__ score) {
  int b = blockIdx.x;
  int lane = threadIdx.x;
  float s = 0.f;
  #pragma unroll
  for (int k = 0; k < 8; ++k) {
    int t = lane + 64 * k;
    int y = ytrue[b * T_ + t];
    int m = masks[t * 128 + b];
    float x = yp[((size_t)b * T_ + t) * K_ + y];
    if (m) s += x;
    if (t >= 1) {
      int ym = ytrue[b * T_ + t - 1];
      int mm = masks[(t - 1) * 128 + b];
      if (m && mm) s += trans[ym * K_ + y];
    }
  }
  #pragma unroll
  for (int off = 32; off; off >>= 1) s += __shfl_xor(s, off, 64);
  if (lane == 0) score[b] = s;
}

// ---------- r6-based scan, templated with ablation VAR ----------
// VAR 0 = full (correct); 1 = no s_barrier; 2 = no MFMA (reads kept live);
// 3 = single ds_read reused for all kb.

template<int TM4, bool RESC, bool MWR, bool MASKED, int VAR>
__device__ __forceinline__ void crf_step(
    int t, int c, int g, int wv, const int* tb,
    const short8 (&Ef)[2][8],
    float (&a)[8], float (&exf)[8], int& acc, int& mkc,
    const float* xb, float4 (&XN)[2], float4 (&XI)[2],
    unsigned short (*Wl)[NB * WROW], const unsigned char* mkl, unsigned int* Mpart) {
  if constexpr (VAR == 1) {
    asm volatile("s_waitcnt lgkmcnt(0)" ::: "memory");
  } else {
    BAR();
  }
  if (RESC) {
    unsigned int Mx = Mpart[c];
    #pragma unroll
    for (int w = 1; w < 8; ++w) Mx = umax_(Mx, Mpart[w * NB + c]);
    unsigned int e_ = Mx >> 23;
    float sf = bits2f((254u - e_) << 23);
    if (!MASKED || mkc) acc += 127 - (int)e_;
    #pragma unroll
    for (int j = 0; j < 8; ++j) exf[j] *= sf;
  }
  f32x4 ac0 = {0.f, 0.f, 0.f, 0.f}, ac1 = {0.f, 0.f, 0.f, 0.f};
  {
    const unsigned short* rrow = &Wl[TM4 & 1][c * WROW];
    if constexpr (VAR == 2) {
      #pragma unroll
      for (int kb = 0; kb < 8; ++kb) {
        uint4 u = *(const uint4*)(&rrow[kb * 32 + g * 8]);
        asm volatile("" :: "v"(u.x), "v"(u.y), "v"(u.z), "v"(u.w));
      }
      #pragma unroll
      for (int i = 0; i < 4; ++i) { ac0[i] = exf[i]; ac1[i] = exf[4 + i]; }
    } else if constexpr (VAR == 3) {
      short8 bf0 = __builtin_bit_cast(short8, *(const uint4*)(&rrow[g * 8]));
      #pragma unroll
      for (int kb = 0; kb < 8; ++kb) {
        ac0 = __builtin_amdgcn_mfma_f32_16x16x32_bf16(Ef[0][kb], bf0, ac0, 0, 0, 0);
        ac1 = __builtin_amdgcn_mfma_f32_16x16x32_bf16(Ef[1][kb], bf0, ac1, 0, 0, 0);
      }
    } else {
      #pragma unroll
      for (int kb = 0; kb < 8; ++kb) {
        short8 bf = __builtin_bit_cast(short8, *(const uint4*)(&rrow[kb * 32 + g * 8]));
        ac0 = __builtin_amdgcn_mfma_f32_16x16x32_bf16(Ef[0][kb], bf, ac0, 0, 0, 0);
        ac1 = __builtin_amdgcn_mfma_f32_16x16x32_bf16(Ef[1][kb], bf, ac1, 0, 0, 0);
      }
    }
  }
  if (MASKED) {
    #pragma unroll
    for (int i = 0; i < 4; ++i) { float an = ac0[i] * exf[i];     a[i]     = mkc ? an : a[i]; }
    #pragma unroll
    for (int i = 0; i < 4; ++i) { float an = ac1[i] * exf[4 + i]; a[4 + i] = mkc ? an : a[4 + i]; }
  } else {
    #pragma unroll
    for (int i = 0; i < 4; ++i) a[i]     = ac0[i] * exf[i];
    #pragma unroll
    for (int i = 0; i < 4; ++i) a[4 + i] = ac1[i] * exf[4 + i];
  }
  {
    unsigned short* wrow = &Wl[(TM4 + 1) & 1][c * WROW];
    #pragma unroll
    for (int m = 0; m < 2; ++m) {
      uint2 pp;
      pp.x = cvt_pk_bf16(a[4 * m + 0], a[4 * m + 1]);
      pp.y = cvt_pk_bf16(a[4 * m + 2], a[4 * m + 3]);
      *(uint2*)(&wrow[tb[m]]) = pp;
    }
  }
  if (MWR) {
    unsigned int pm = f2bits(a[0]);
    #pragma unroll
    for (int j = 1; j < 8; ++j) pm = umax_(pm, f2bits(a[j]));
    pm = umax_(pm, (unsigned int)__shfl_xor((int)pm, 16, 64));
    pm = umax_(pm, (unsigned int)__shfl_xor((int)pm, 32, 64));
    if (g == 0) Mpart[wv * NB + c] = pm;
  }
  #pragma unroll
  for (int m = 0; m < 2; ++m) {
    exf[4 * m + 0] = fexp2(XN[m].x * L2E);
    exf[4 * m + 1] = fexp2(XN[m].y * L2E);
    exf[4 * m + 2] = fexp2(XN[m].z * L2E);
    exf[4 * m + 3] = fexp2(XN[m].w * L2E);
  }
  if (MASKED) mkc = mkl[(t + 1 < T_ ? t + 1 : 0) * NB + c];
  {
    int tt = t + 4;
    tt = tt > (T_ - 1) ? (T_ - 1) : tt;
    #pragma unroll
    for (int m = 0; m < 2; ++m)
      XI[m] = *(const float4*)(xb + (size_t)tt * K_ + tb[m]);
  }
}

template<bool MASKED, int VAR>
__device__ __forceinline__ void scan_run(
    int tid, int c, int g, int wv, const int* tb, int b0,
    const short8 (&Ef)[2][8], const float* xb,
    float4 (&xinit)[2], float4 (&X0q)[2], float4 (&X1q)[2],
    float4 (&X2q)[2], float4 (&X3q)[2],
    unsigned short (*Wl)[NB * WROW], const unsigned char* mkl,
    unsigned int* Mpart, float* Spart,
    const float* __restrict__ score, float* __restrict__ outp) {
  float a[8], exf[8];
  int acc = 0;
  int mkc = 0;
  {
    int mk0 = MASKED ? mkl[c] : 1;
    #pragma unroll
    for (int m = 0; m < 2; ++m) {
      float e0 = fexp2(xinit[m].x * L2E);
      float e1 = fexp2(xinit[m].y * L2E);
      float e2 = fexp2(xinit[m].z * L2E);
      float e3 = fexp2(xinit[m].w * L2E);
      a[4 * m + 0] = (MASKED && !mk0) ? 1.0f : e0;
      a[4 * m + 1] = (MASKED && !mk0) ? 1.0f : e1;
      a[4 * m + 2] = (MASKED && !mk0) ? 1.0f : e2;
      a[4 * m + 3] = (MASKED && !mk0) ? 1.0f : e3;
    }
  }
  {
    unsigned short* wrow = &Wl[1][c * WROW];
    #pragma unroll
    for (int m = 0; m < 2; ++m) {
      uint2 pp;
      pp.x = cvt_pk_bf16(a[4 * m + 0], a[4 * m + 1]);
      pp.y = cvt_pk_bf16(a[4 * m + 2], a[4 * m + 3]);
      *(uint2*)(&wrow[tb[m]]) = pp;
    }
  }
  #pragma unroll
  for (int m = 0; m < 2; ++m) {
    exf[4 * m + 0] = fexp2(X1q[m].x * L2E);
    exf[4 * m + 1] = fexp2(X1q[m].y * L2E);
    exf[4 * m + 2] = fexp2(X1q[m].z * L2E);
    exf[4 * m + 3] = fexp2(X1q[m].w * L2E);
  }
  if (MASKED) mkc = mkl[NB + c];

  crf_step<1, false, false, MASKED, VAR>(1, c, g, wv, tb, Ef, a, exf, acc, mkc, xb, X2q, X1q, Wl, mkl, Mpart);
  crf_step<2, false, false, MASKED, VAR>(2, c, g, wv, tb, Ef, a, exf, acc, mkc, xb, X3q, X2q, Wl, mkl, Mpart);
  crf_step<3, false, true , MASKED, VAR>(3, c, g, wv, tb, Ef, a, exf, acc, mkc, xb, X0q, X3q, Wl, mkl, Mpart);

  #pragma unroll 1
  for (int t0 = 4; t0 < T_; t0 += 4) {
    crf_step<0, true , false, MASKED, VAR>(t0,     c, g, wv, tb, Ef, a, exf, acc, mkc, xb, X1q, X0q, Wl, mkl, Mpart);
    crf_step<1, false, false, MASKED, VAR>(t0 + 1, c, g, wv, tb, Ef, a, exf, acc, mkc, xb, X2q, X1q, Wl, mkl, Mpart);
    crf_step<2, false, false, MASKED, VAR>(t0 + 2, c, g, wv, tb, Ef, a, exf, acc, mkc, xb, X3q, X2q, Wl, mkl, Mpart);
    crf_step<3, false, true , MASKED, VAR>(t0 + 3, c, g, wv, tb, Ef, a, exf, acc, mkc, xb, X0q, X3q, Wl, mkl, Mpart);
  }

  __syncthreads();
  {
    float ssum = 0.f;
    #pragma unroll
    for (int j = 0; j < 8; ++j) ssum += a[j];
    ssum += __shfl_xor(ssum, 16, 64);
    ssum += __shfl_xor(ssum, 32, 64);
    if (g == 0) Spart[wv * NB + c] = ssum;
  }
  __syncthreads();
  if (tid < NB) {
    float S = 0.f;
    #pragma unroll
    for (int w = 0; w < 8; ++w) S += Spart[w * NB + tid];
    outp[b0 + tid] = LN2 * (flog2(S) - (float)acc) - score[b0 + tid];
  }
}

template<int VAR>
__global__ __launch_bounds__(512, 1) void crf_scan(
    const float* __restrict__ yp, const unsigned short* __restrict__ Efrag,
    const unsigned char* __restrict__ masks, const float* __restrict__ score,
    float* __restrict__ outp) {
  const int b0 = blockIdx.x * NB;
  const int tid = threadIdx.x;
  const int wv = tid >> 6, lane = tid & 63;
  const int c = lane & 15;
  const int g = lane >> 4;

  __shared__ unsigned short Wl[2][NB * WROW];
  __shared__ unsigned char mkl[T_ * NB];
  __shared__ unsigned int Mpart[8 * NB];
  __shared__ float Spart[8 * NB];
  __shared__ int sflag[8];

  short8 Ef[2][8];
  {
    const uint4* ep = (const uint4*)Efrag;
    #pragma unroll
    for (int m = 0; m < 2; ++m)
      #pragma unroll
      for (int kb = 0; kb < 8; ++kb)
        Ef[m][kb] = __builtin_bit_cast(short8, ep[((wv * 2 + m) * 8 + kb) * 64 + lane]);
  }

  uint4 md0;
  {
    uint4* dst = (uint4*)mkl;
    md0 = *(const uint4*)(masks + tid * 128 + b0);
    dst[tid] = md0;
  }

  const float* xb = yp + (size_t)(b0 + c) * T_ * K_;
  int tb[2];
  #pragma unroll
  for (int m = 0; m < 2; ++m) tb[m] = wv * 32 + m * 16 + g * 4;

  float4 xinit[2], X0q[2], X1q[2], X2q[2], X3q[2];
  #pragma unroll
  for (int m = 0; m < 2; ++m) xinit[m] = *(const float4*)(xb + tb[m]);
  #pragma unroll
  for (int m = 0; m < 2; ++m) X1q[m] = *(const float4*)(xb + 1 * K_ + tb[m]);
  #pragma unroll
  for (int m = 0; m < 2; ++m) X2q[m] = *(const float4*)(xb + 2 * K_ + tb[m]);
  #pragma unroll
  for (int m = 0; m < 2; ++m) X3q[m] = *(const float4*)(xb + 3 * K_ + tb[m]);
  #pragma unroll
  for (int m = 0; m < 2; ++m) X0q[m] = *(const float4*)(xb + 4 * K_ + tb[m]);

  {
    uint32_t w = md0.x & md0.y & md0.z & md0.w;
    unsigned long long bl = __ballot(w == 0x01010101u);
    if (lane == 0) sflag[wv] = (bl == ~0ull) ? 1 : 0;
  }
  __syncthreads();
  bool allm = true;
  #pragma unroll
  for (int w = 0; w < 8; ++w) allm = allm && sflag[w];

  if (allm) {
    scan_run<false, VAR>(tid, c, g, wv, tb, b0, Ef, xb, xinit, X0q, X1q, X2q, X3q,
                         Wl, mkl, Mpart, Spart, score, outp);
  } else {
    scan_run<true, VAR>(tid, c, g, wv, tb, b0, Ef, xb, xinit, X0q, X1q, X2q, X3q,
                        Wl, mkl, Mpart, Spart, score, outp);
  }
}

// ---------- MX probe (r11 body, non-PRE; timing only, writes scratch) ----------

struct SlotF { float4 f0, f1; };

__device__ __forceinline__ void slot_loadF(SlotF& s, const float* base, int tt, int off0) {
  const float* p = base + (size_t)tt * K_ + off0;
  s.f0 = *(const float4*)(p);
  s.f1 = *(const float4*)(p + 16);
}
__device__ __forceinline__ void slot_exfF(const SlotF& s, float (&exf)[8]) {
  exf[0] = fexp2(s.f0.x * L2E); exf[1] = fexp2(s.f0.y * L2E);
  exf[2] = fexp2(s.f0.z * L2E); exf[3] = fexp2(s.f0.w * L2E);
  exf[4] = fexp2(s.f1.x * L2E); exf[5] = fexp2(s.f1.y * L2E);
  exf[6] = fexp2(s.f1.z * L2E); exf[7] = fexp2(s.f1.w * L2E);
}

__device__ __forceinline__ void pack_w_tau(
    const float (&a)[8], unsigned char* wrowbase, unsigned char* trow,
    int c, int g, int wv, int lane) {
  uint32_t pm = f2bits(a[0]);
  #pragma unroll
  for (int j = 1; j < 8; ++j) pm = umax_(pm, f2bits(a[j]));
  pm = umax_(pm, (uint32_t)__shfl_xor((int)pm, 16, 64));
  pm = umax_(pm, (uint32_t)__shfl_xor((int)pm, 32, 64));
  uint32_t Eb = pm >> 23;
  int scb = 257 - (int)Eb;
  scb = scb < 1 ? 1 : (scb > 254 ? 254 : scb);
  float sc = bits2f((uint32_t)scb << 23);
  uint32_t tn = Eb >= 3 ? (Eb - 3) : 0;
  if (tn > 254) tn = 254;
  uint32_t p0 = pk_fp8<false>(a[0] * sc, a[1] * sc, 0u);
  p0 = pk_fp8<true>(a[2] * sc, a[3] * sc, p0);
  uint32_t p1 = pk_fp8<false>(a[4] * sc, a[5] * sc, 0u);
  p1 = pk_fp8<true>(a[6] * sc, a[7] * sc, p1);
  unsigned char* wp = wrowbase + c * WSTR + ((wv ^ (c & 3)) << 5) + 4 * g;
  *(uint32_t*)(wp) = p0;
  *(uint32_t*)(wp + 16) = p1;
  if (lane < 16) trow[c * 8 + wv] = (unsigned char)tn;
}

template<int TM4>
__device__ __forceinline__ void crf_step_mx(
    int t, int c, int g, int wv, int lane, int off0, int rbase,
    const int8v (&Ef)[2][2],
    float (&a)[8], float (&exf)[8], int& R,
    const float* xbase, SlotF& XN, SlotF& XI,
    unsigned char (*Wl)[NB * WSTR], unsigned char (*Tl)[NB * 8]) {
  BAR();
  const int par = TM4 & 1;
  uint2 trow = *(const uint2*)&Tl[par][c * 8];
  uint32_t tb0 = (trow.x >> (8 * g)) & 255u;
  uint32_t tb1 = (trow.y >> (8 * g)) & 255u;
  uint32_t mx;
  {
    uint32_t x = trow.x, y = trow.y;
    uint32_t m0 = umax_(x & 255u, (x >> 8) & 255u);
    uint32_t m1 = umax_((x >> 16) & 255u, x >> 24);
    uint32_t m2 = umax_(y & 255u, (y >> 8) & 255u);
    uint32_t m3 = umax_((y >> 16) & 255u, y >> 24);
    mx = umax_(umax_(m0, m1), umax_(m2, m3));
  }
  int dlt = (int)mx - 127;
  int s0 = (int)tb0 - (int)mx + 127; s0 = s0 < 0 ? 0 : s0;
  int s1 = (int)tb1 - (int)mx + 127; s1 = s1 < 0 ? 0 : s1;
  const unsigned char* rp = &Wl[par][rbase];
  uint4 u0 = *(const uint4*)(rp);
  uint4 u1 = *(const uint4*)(rp + 16);
  uint4 u2 = *(const uint4*)(rp + 128);
  uint4 u3 = *(const uint4*)(rp + 144);
  int8v B0, B1;
  B0[0] = u0.x; B0[1] = u0.y; B0[2] = u0.z; B0[3] = u0.w;
  B0[4] = u1.x; B0[5] = u1.y; B0[6] = u1.z; B0[7] = u1.w;
  B1[0] = u2.x; B1[1] = u2.y; B1[2] = u2.z; B1[3] = u2.w;
  B1[4] = u3.x; B1[5] = u3.y; B1[6] = u3.z; B1[7] = u3.w;
  f32x4 z = {0.f, 0.f, 0.f, 0.f};
  f32x4 ac0 = __builtin_amdgcn_mfma_scale_f32_16x16x128_f8f6f4(
      Ef[0][0], B0, z, 0, 0, 0, 127, 0, s0);
  ac0 = __builtin_amdgcn_mfma_scale_f32_16x16x128_f8f6f4(
      Ef[0][1], B1, ac0, 0, 0, 0, 127, 0, s1);
  f32x4 ac1 = __builtin_amdgcn_mfma_scale_f32_16x16x128_f8f6f4(
      Ef[1][0], B0, z, 0, 0, 0, 127, 0, s0);
  ac1 = __builtin_amdgcn_mfma_scale_f32_16x16x128_f8f6f4(
      Ef[1][1], B1, ac1, 0, 0, 0, 127, 0, s1);
  R += dlt;
  #pragma unroll
  for (int i = 0; i < 4; ++i) a[i]     = ac0[i] * exf[i];
  #pragma unroll
  for (int i = 0; i < 4; ++i) a[4 + i] = ac1[i] * exf[4 + i];
  pack_w_tau(a, Wl[par ^ 1], Tl[par ^ 1], c, g, wv, lane);
  slot_exfF(XN, exf);
  {
    int tt = t + 4;
    tt = tt > (T_ - 1) ? (T_ - 1) : tt;
    slot_loadF(XI, xbase, tt, off0);
  }
}

__global__ __launch_bounds__(512, 1) void crf_scan_mx(
    const float* __restrict__ yp, const unsigned char* __restrict__ Efrag,
    const float* __restrict__ score, float* __restrict__ outp) {
  const int b0 = blockIdx.x * NB;
  const int tid = threadIdx.x;
  const int wv = tid >> 6, lane = tid & 63;
  const int c = lane & 15;
  const int g = lane >> 4;
  const int off0 = 32 * wv + 4 * g;
  const int qs = g ^ (c & 3);
  const int rbase = c * WSTR + (qs << 5);

  __shared__ unsigned char Wl[2][NB * WSTR];
  __shared__ unsigned char Tl[2][NB * 8];
  __shared__ float Spart[8 * NB];

  int8v Ef[2][2];
  {
    #pragma unroll
    for (int m = 0; m < 2; ++m)
      #pragma unroll
      for (int h = 0; h < 2; ++h) {
        const uint4* ep = (const uint4*)(Efrag + (size_t)(((wv * 2 + m) * 2 + h) * 64 + lane) * 32);
        uint4 e0 = ep[0], e1 = ep[1];
        int8v v;
        v[0] = e0.x; v[1] = e0.y; v[2] = e0.z; v[3] = e0.w;
        v[4] = e1.x; v[5] = e1.y; v[6] = e1.z; v[7] = e1.w;
        Ef[m][h] = v;
      }
  }

  const float* xbase = yp + (size_t)(b0 + c) * T_ * K_;

  SlotF Sinit, S0, S1, S2, S3;
  slot_loadF(Sinit, xbase, 0, off0);
  slot_loadF(S1, xbase, 1, off0);
  slot_loadF(S2, xbase, 2, off0);
  slot_loadF(S3, xbase, 3, off0);
  slot_loadF(S0, xbase, 4, off0);

  float a[8], exf[8];
  int R = 0;
  {
    float e0[8];
    slot_exfF(Sinit, e0);
    #pragma unroll
    for (int j = 0; j < 8; ++j) a[j] = e0[j];
  }
  pack_w_tau(a, Wl[1], Tl[1], c, g, wv, lane);
  slot_exfF(S1, exf);
  __syncthreads();

  crf_step_mx<1>(1, c, g, wv, lane, off0, rbase, Ef, a, exf, R, xbase, S2, S1, Wl, Tl);
  crf_step_mx<2>(2, c, g, wv, lane, off0, rbase, Ef, a, exf, R, xbase, S3, S2, Wl, Tl);
  crf_step_mx<3>(3, c, g, wv, lane, off0, rbase, Ef, a, exf, R, xbase, S0, S3, Wl, Tl);
  #pragma unroll 1
  for (int t0 = 4; t0 < T_; t0 += 4) {
    crf_step_mx<0>(t0,     c, g, wv, lane, off0, rbase, Ef, a, exf, R, xbase, S1, S0, Wl, Tl);
    crf_step_mx<1>(t0 + 1, c, g, wv, lane, off0, rbase, Ef, a, exf, R, xbase, S2, S1, Wl, Tl);
    crf_step_mx<2>(t0 + 2, c, g, wv, lane, off0, rbase, Ef, a, exf, R, xbase, S3, S2, Wl, Tl);
    crf_step_mx<3>(t0 + 3, c, g, wv, lane, off0, rbase, Ef, a, exf, R, xbase, S0, S3, Wl, Tl);
  }

  __syncthreads();
  {
    float ssum = 0.f;
    #pragma unroll
    for (int j = 0; j < 8; ++j) ssum += a[j];
    ssum += __shfl_xor(ssum, 16, 64);
    ssum += __shfl_xor(ssum, 32, 64);
    if (g == 0) Spart[wv * NB + c] = ssum;
  }
  __syncthreads();
  if (tid < NB) {
    float S = 0.f;
    #pragma unroll
    for (int w = 0; w < 8; ++w) S += Spart[w * NB + tid];
    outp[b0 + tid] = LN2 * (flog2(S) + (float)R) - score[b0 + tid];
  }
}

extern "C" void kernel_launch(void* const* d_in, const int* in_sizes, int n_in,
                              void* d_out, int out_size, void* d_ws, size_t ws_size,
                              hipStream_t stream) {
  const float* yp = (const float*)d_in[0];
  const float* trans = (const float*)d_in[1];
  const int* ytrue = (const int*)d_in[2];
  float* out = (float*)d_out;

  unsigned short* Efb = (unsigned short*)d_ws;                    // 128 KB
  unsigned char* Efm = (unsigned char*)d_ws + 131072;             // 64 KB
  unsigned char* masks = (unsigned char*)d_ws + 196608;           // 64 KB
  float* score = (float*)((char*)d_ws + 262144);                  // 512 B
  float* probe = (float*)((char*)d_ws + 262656);                  // 512 B

  prep_E_bf<<<dim3(256), dim3(256), 0, stream>>>(trans, Efb);
  prep_E_mx<<<dim3(256), dim3(256), 0, stream>>>(trans, Efm);
  aux_mask<<<dim3(16384), dim3(256), 0, stream>>>(yp, masks);
  aux_score<<<dim3(128), dim3(64), 0, stream>>>(yp, trans, ytrue, masks, score);

  // --- timing probes (write scratch; numerics irrelevant) ---
  crf_scan_mx<<<dim3(8), dim3(512), 0, stream>>>(yp, Efm, score, probe);      // V4 MX
  crf_scan<1><<<dim3(8), dim3(512), 0, stream>>>(yp, Efb, masks, score, probe); // V1 noBAR
  crf_scan<2><<<dim3(8), dim3(512), 0, stream>>>(yp, Efb, masks, score, probe); // V2 noMFMA
  crf_scan<3><<<dim3(8), dim3(512), 0, stream>>>(yp, Efb, masks, score, probe); // V3 read1

  // --- the real kernel, last, owns d_out ---
  crf_scan<0><<<dim3(8), dim3(512), 0, stream>>>(yp, Efb, masks, score, out);   // V0 full
}

// Round 13
// 480.345 us; speedup vs baseline: 2.6711x; 2.6711x over previous
//
#include <hip/hip_runtime.h>
#include <stdint.h>

#define T_ 512
#define K_ 256
#define NB 16
#define MKS 32     // mask-table row stride (32 batches/block)
#define WROW 264   // bf16 W row stride in ushorts
#define L2E 1.4426950408889634f
#define LN2 0.6931471805599453f

typedef __attribute__((ext_vector_type(8))) short short8;
typedef __attribute__((ext_vector_type(4))) float f32x4;

__device__ __forceinline__ float fexp2(float x) {
#if __has_builtin(__builtin_amdgcn_exp2f)
  return __builtin_amdgcn_exp2f(x);
#else
  return exp2f(x);
#endif
}
__device__ __forceinline__ float flog2(float x) {
#if __has_builtin(__builtin_amdgcn_logf)
  return __builtin_amdgcn_logf(x);
#else
  return log2f(x);
#endif
}
__device__ __forceinline__ unsigned int umax_(unsigned int a, unsigned int b) {
  return a > b ? a : b;
}
__device__ __forceinline__ float bits2f(uint32_t u) { return __builtin_bit_cast(float, u); }
__device__ __forceinline__ uint32_t f2bits(float f) { return __builtin_bit_cast(uint32_t, f); }

__device__ __forceinline__ unsigned short f2bf(float f) {
  union { float f; uint32_t u; } v; v.f = f;
  uint32_t r = v.u + 0x7fffu + ((v.u >> 16) & 1u);
  return (unsigned short)(r >> 16);
}
__device__ __forceinline__ uint32_t cvt_pk_bf16(float a, float b) {
  uint32_t d;
  asm("v_cvt_pk_bf16_f32 %0, %1, %2" : "=v"(d) : "v"(a), "v"(b));
  return d;
}

#define BAR() do { \
  asm volatile("s_waitcnt lgkmcnt(0)" ::: "memory"); \
  __builtin_amdgcn_s_barrier(); \
  asm volatile("" ::: "memory"); \
} while (0)

// ---------- aux kernels (proven) ----------

__global__ void prep_E(const float* __restrict__ trans, unsigned short* __restrict__ Efrag) {
  int idx = blockIdx.x * 256 + threadIdx.x;
  int e = idx & 7;
  int ln = (idx >> 3) & 63;
  int kb = (idx >> 9) & 7;
  int mt = idx >> 12;
  int j = mt * 16 + (ln & 15);
  int k = kb * 32 + ((ln >> 4) << 3) + e;
  Efrag[idx] = f2bf(__expf(trans[k * K_ + j]));
}

__global__ void aux_mask(const float* __restrict__ yp, unsigned char* __restrict__ masks) {
  int item = blockIdx.x * 4 + (threadIdx.x >> 6);
  int lane = threadIdx.x & 63;
  const float4 v = *(const float4*)(yp + (size_t)item * K_ + lane * 4);
  float mn = fminf(fminf(v.x, v.y), fminf(v.z, v.w));
  unsigned long long bl = __ballot(mn > -1000000.0f);
  if (lane == 0) {
    int b = item >> 9, t = item & 511;
    masks[t * 128 + b] = (bl == ~0ull) ? 1 : 0;
  }
}

__global__ void aux_score(const float* __restrict__ yp, const float* __restrict__ trans,
                          const int* __restrict__ ytrue, const unsigned char* __restrict__ masks,
                          float* __restrict__ score) {
  int b = blockIdx.x;
  int lane = threadIdx.x;
  float s = 0.f;
  #pragma unroll
  for (int k = 0; k < 8; ++k) {
    int t = lane + 64 * k;
    int y = ytrue[b * T_ + t];
    int m = masks[t * 128 + b];
    float x = yp[((size_t)b * T_ + t) * K_ + y];
    if (m) s += x;
    if (t >= 1) {
      int ym = ytrue[b * T_ + t - 1];
      int mm = masks[(t - 1) * 128 + b];
      if (m && mm) s += trans[ym * K_ + y];
    }
  }
  #pragma unroll
  for (int off = 32; off; off >>= 1) s += __shfl_xor(s, off, 64);
  if (lane == 0) score[b] = s;
}

// ---------- scan: 8 waves, TWO independent batch groups per block ----------
// One step for ONE group; the caller places the barrier.

template<int TM4, bool RESC, bool MWR, bool MASKED>
__device__ __forceinline__ void crf_step(
    int t, int c, int g, int wv, const int* tb,
    const short8 (&Ef)[2][8],
    float (&a)[8], float (&exf)[8], int& acc, int& mkc,
    const float* xb, float4 (&XN)[2], float4 (&XI)[2],
    unsigned short (*Wl)[NB * WROW], const unsigned char* mkl, unsigned int* Mpart) {
  if (RESC) {
    unsigned int Mx = Mpart[c];
    #pragma unroll
    for (int w = 1; w < 8; ++w) Mx = umax_(Mx, Mpart[w * NB + c]);
    unsigned int e_ = Mx >> 23;
    float sf = bits2f((254u - e_) << 23);
    if (!MASKED || mkc) acc += 127 - (int)e_;
    #pragma unroll
    for (int j = 0; j < 8; ++j) exf[j] *= sf;
  }
  f32x4 ac0 = {0.f, 0.f, 0.f, 0.f}, ac1 = {0.f, 0.f, 0.f, 0.f};
  {
    const unsigned short* rrow = &Wl[TM4 & 1][c * WROW];
    #pragma unroll
    for (int kb = 0; kb < 8; ++kb) {
      short8 bf = __builtin_bit_cast(short8, *(const uint4*)(&rrow[kb * 32 + g * 8]));
      ac0 = __builtin_amdgcn_mfma_f32_16x16x32_bf16(Ef[0][kb], bf, ac0, 0, 0, 0);
      ac1 = __builtin_amdgcn_mfma_f32_16x16x32_bf16(Ef[1][kb], bf, ac1, 0, 0, 0);
    }
  }
  if (MASKED) {
    #pragma unroll
    for (int i = 0; i < 4; ++i) { float an = ac0[i] * exf[i];     a[i]     = mkc ? an : a[i]; }
    #pragma unroll
    for (int i = 0; i < 4; ++i) { float an = ac1[i] * exf[4 + i]; a[4 + i] = mkc ? an : a[4 + i]; }
  } else {
    #pragma unroll
    for (int i = 0; i < 4; ++i) a[i]     = ac0[i] * exf[i];
    #pragma unroll
    for (int i = 0; i < 4; ++i) a[4 + i] = ac1[i] * exf[4 + i];
  }
  {
    unsigned short* wrow = &Wl[(TM4 + 1) & 1][c * WROW];
    #pragma unroll
    for (int m = 0; m < 2; ++m) {
      uint2 pp;
      pp.x = cvt_pk_bf16(a[4 * m + 0], a[4 * m + 1]);
      pp.y = cvt_pk_bf16(a[4 * m + 2], a[4 * m + 3]);
      *(uint2*)(&wrow[tb[m]]) = pp;
    }
  }
  if (MWR) {
    unsigned int pm = f2bits(a[0]);
    #pragma unroll
    for (int j = 1; j < 8; ++j) pm = umax_(pm, f2bits(a[j]));
    pm = umax_(pm, (unsigned int)__shfl_xor((int)pm, 16, 64));
    pm = umax_(pm, (unsigned int)__shfl_xor((int)pm, 32, 64));
    if (g == 0) Mpart[wv * NB + c] = pm;
  }
  #pragma unroll
  for (int m = 0; m < 2; ++m) {
    exf[4 * m + 0] = fexp2(XN[m].x * L2E);
    exf[4 * m + 1] = fexp2(XN[m].y * L2E);
    exf[4 * m + 2] = fexp2(XN[m].z * L2E);
    exf[4 * m + 3] = fexp2(XN[m].w * L2E);
  }
  if (MASKED) mkc = mkl[(t + 1 < T_ ? t + 1 : 0) * MKS + c];
  {
    int tt = t + 4;
    tt = tt > (T_ - 1) ? (T_ - 1) : tt;
    #pragma unroll
    for (int m = 0; m < 2; ++m)
      XI[m] = *(const float4*)(xb + (size_t)tt * K_ + tb[m]);
  }
}

// per-group state bundle lives in named locals of scan_run (rule #20: no
// runtime-indexed arrays).

template<bool MASKED>
__device__ __forceinline__ void scan_run(
    int tid, int c, int g, int wv, const int* tb, int b0,
    const short8 (&Ef)[2][8],
    const float* xbA, const float* xbB,
    unsigned short (*WlA)[NB * WROW], unsigned short (*WlB)[NB * WROW],
    const unsigned char* mklA, const unsigned char* mklB,
    unsigned int* MpA, unsigned int* MpB, float* SpA, float* SpB,
    const float* __restrict__ score, float* __restrict__ out) {
  float aA[8], exfA[8], aB[8], exfB[8];
  int accA = 0, mkcA = 0, accB = 0, mkcB = 0;
  float4 A0[2], A1[2], A2[2], A3[2];
  float4 B0[2], B1[2], B2[2], B3[2];

  // initial loads: t=0..4 for both groups
  {
    float4 xiA[2], xiB[2];
    #pragma unroll
    for (int m = 0; m < 2; ++m) {
      xiA[m] = *(const float4*)(xbA + tb[m]);
      xiB[m] = *(const float4*)(xbB + tb[m]);
      A1[m] = *(const float4*)(xbA + 1 * K_ + tb[m]);
      B1[m] = *(const float4*)(xbB + 1 * K_ + tb[m]);
      A2[m] = *(const float4*)(xbA + 2 * K_ + tb[m]);
      B2[m] = *(const float4*)(xbB + 2 * K_ + tb[m]);
      A3[m] = *(const float4*)(xbA + 3 * K_ + tb[m]);
      B3[m] = *(const float4*)(xbB + 3 * K_ + tb[m]);
      A0[m] = *(const float4*)(xbA + 4 * K_ + tb[m]);
      B0[m] = *(const float4*)(xbB + 4 * K_ + tb[m]);
    }
    int mkA0 = MASKED ? mklA[c] : 1;
    int mkB0 = MASKED ? mklB[c] : 1;
    #pragma unroll
    for (int m = 0; m < 2; ++m) {
      aA[4 * m + 0] = (MASKED && !mkA0) ? 1.0f : fexp2(xiA[m].x * L2E);
      aA[4 * m + 1] = (MASKED && !mkA0) ? 1.0f : fexp2(xiA[m].y * L2E);
      aA[4 * m + 2] = (MASKED && !mkA0) ? 1.0f : fexp2(xiA[m].z * L2E);
      aA[4 * m + 3] = (MASKED && !mkA0) ? 1.0f : fexp2(xiA[m].w * L2E);
      aB[4 * m + 0] = (MASKED && !mkB0) ? 1.0f : fexp2(xiB[m].x * L2E);
      aB[4 * m + 1] = (MASKED && !mkB0) ? 1.0f : fexp2(xiB[m].y * L2E);
      aB[4 * m + 2] = (MASKED && !mkB0) ? 1.0f : fexp2(xiB[m].z * L2E);
      aB[4 * m + 3] = (MASKED && !mkB0) ? 1.0f : fexp2(xiB[m].w * L2E);
    }
  }
  // W[1] <- bf16(alpha(0)) for both groups
  {
    unsigned short* wrA = &WlA[1][c * WROW];
    unsigned short* wrB = &WlB[1][c * WROW];
    #pragma unroll
    for (int m = 0; m < 2; ++m) {
      uint2 pa, pb;
      pa.x = cvt_pk_bf16(aA[4 * m + 0], aA[4 * m + 1]);
      pa.y = cvt_pk_bf16(aA[4 * m + 2], aA[4 * m + 3]);
      pb.x = cvt_pk_bf16(aB[4 * m + 0], aB[4 * m + 1]);
      pb.y = cvt_pk_bf16(aB[4 * m + 2], aB[4 * m + 3]);
      *(uint2*)(&wrA[tb[m]]) = pa;
      *(uint2*)(&wrB[tb[m]]) = pb;
    }
  }
  #pragma unroll
  for (int m = 0; m < 2; ++m) {
    exfA[4 * m + 0] = fexp2(A1[m].x * L2E);
    exfA[4 * m + 1] = fexp2(A1[m].y * L2E);
    exfA[4 * m + 2] = fexp2(A1[m].z * L2E);
    exfA[4 * m + 3] = fexp2(A1[m].w * L2E);
    exfB[4 * m + 0] = fexp2(B1[m].x * L2E);
    exfB[4 * m + 1] = fexp2(B1[m].y * L2E);
    exfB[4 * m + 2] = fexp2(B1[m].z * L2E);
    exfB[4 * m + 3] = fexp2(B1[m].w * L2E);
  }
  if (MASKED) { mkcA = mklA[MKS + c]; mkcB = mklB[MKS + c]; }

  // prologue t = 1..3
  BAR();
  crf_step<1, false, false, MASKED>(1, c, g, wv, tb, Ef, aA, exfA, accA, mkcA, xbA, A2, A1, WlA, mklA, MpA);
  crf_step<1, false, false, MASKED>(1, c, g, wv, tb, Ef, aB, exfB, accB, mkcB, xbB, B2, B1, WlB, mklB, MpB);
  BAR();
  crf_step<2, false, false, MASKED>(2, c, g, wv, tb, Ef, aA, exfA, accA, mkcA, xbA, A3, A2, WlA, mklA, MpA);
  crf_step<2, false, false, MASKED>(2, c, g, wv, tb, Ef, aB, exfB, accB, mkcB, xbB, B3, B2, WlB, mklB, MpB);
  BAR();
  crf_step<3, false, true , MASKED>(3, c, g, wv, tb, Ef, aA, exfA, accA, mkcA, xbA, A0, A3, WlA, mklA, MpA);
  crf_step<3, false, true , MASKED>(3, c, g, wv, tb, Ef, aB, exfB, accB, mkcB, xbB, B0, B3, WlB, mklB, MpB);

  #pragma unroll 1
  for (int t0 = 4; t0 < T_; t0 += 4) {
    BAR();
    crf_step<0, true , false, MASKED>(t0,     c, g, wv, tb, Ef, aA, exfA, accA, mkcA, xbA, A1, A0, WlA, mklA, MpA);
    crf_step<0, true , false, MASKED>(t0,     c, g, wv, tb, Ef, aB, exfB, accB, mkcB, xbB, B1, B0, WlB, mklB, MpB);
    BAR();
    crf_step<1, false, false, MASKED>(t0 + 1, c, g, wv, tb, Ef, aA, exfA, accA, mkcA, xbA, A2, A1, WlA, mklA, MpA);
    crf_step<1, false, false, MASKED>(t0 + 1, c, g, wv, tb, Ef, aB, exfB, accB, mkcB, xbB, B2, B1, WlB, mklB, MpB);
    BAR();
    crf_step<2, false, false, MASKED>(t0 + 2, c, g, wv, tb, Ef, aA, exfA, accA, mkcA, xbA, A3, A2, WlA, mklA, MpA);
    crf_step<2, false, false, MASKED>(t0 + 2, c, g, wv, tb, Ef, aB, exfB, accB, mkcB, xbB, B3, B2, WlB, mklB, MpB);
    BAR();
    crf_step<3, false, true , MASKED>(t0 + 3, c, g, wv, tb, Ef, aA, exfA, accA, mkcA, xbA, A0, A3, WlA, mklA, MpA);
    crf_step<3, false, true , MASKED>(t0 + 3, c, g, wv, tb, Ef, aB, exfB, accB, mkcB, xbB, B0, B3, WlB, mklB, MpB);
  }

  // final: logsumexp for both groups
  __syncthreads();
  {
    float sA = 0.f, sB = 0.f;
    #pragma unroll
    for (int j = 0; j < 8; ++j) { sA += aA[j]; sB += aB[j]; }
    sA += __shfl_xor(sA, 16, 64); sA += __shfl_xor(sA, 32, 64);
    sB += __shfl_xor(sB, 16, 64); sB += __shfl_xor(sB, 32, 64);
    if (g == 0) { SpA[wv * NB + c] = sA; SpB[wv * NB + c] = sB; }
  }
  __syncthreads();
  if (tid < NB) {
    float SA = 0.f, SB = 0.f;
    #pragma unroll
    for (int w = 0; w < 8; ++w) { SA += SpA[w * NB + tid]; SB += SpB[w * NB + tid]; }
    out[b0 + tid] = LN2 * (flog2(SA) - (float)accA) - score[b0 + tid];
    out[b0 + NB + tid] = LN2 * (flog2(SB) - (float)accB) - score[b0 + NB + tid];
  }
}

__global__ __launch_bounds__(512, 1) void crf_scan(
    const float* __restrict__ yp, const unsigned short* __restrict__ Efrag,
    const unsigned char* __restrict__ masks, const float* __restrict__ score,
    float* __restrict__ out) {
  const int b0 = blockIdx.x * 32;
  const int tid = threadIdx.x;
  const int wv = tid >> 6, lane = tid & 63;
  const int c = lane & 15;
  const int g = lane >> 4;

  __shared__ unsigned short WlA[2][NB * WROW];  // ~16.9 KB
  __shared__ unsigned short WlB[2][NB * WROW];  // ~16.9 KB
  __shared__ unsigned char mkl[T_ * MKS];       // 16 KB
  __shared__ unsigned int MpA[8 * NB];
  __shared__ unsigned int MpB[8 * NB];
  __shared__ float SpA[8 * NB];
  __shared__ float SpB[8 * NB];
  __shared__ int sflag[8];

  short8 Ef[2][8];
  {
    const uint4* ep = (const uint4*)Efrag;
    #pragma unroll
    for (int m = 0; m < 2; ++m)
      #pragma unroll
      for (int kb = 0; kb < 8; ++kb)
        Ef[m][kb] = __builtin_bit_cast(short8, ep[((wv * 2 + m) * 8 + kb) * 64 + lane]);
  }

  // mask table -> LDS: row t = tid, 32 bytes (batches b0..b0+31)
  uint4 md0, md1;
  {
    md0 = *(const uint4*)(masks + tid * 128 + b0);
    md1 = *(const uint4*)(masks + tid * 128 + b0 + 16);
    *(uint4*)(&mkl[tid * MKS]) = md0;
    *(uint4*)(&mkl[tid * MKS + 16]) = md1;
  }

  const float* xbA = yp + (size_t)(b0 + c) * T_ * K_;
  const float* xbB = yp + (size_t)(b0 + 16 + c) * T_ * K_;
  int tb[2];
  #pragma unroll
  for (int m = 0; m < 2; ++m) tb[m] = wv * 32 + m * 16 + g * 4;

  {
    uint32_t w = md0.x & md0.y & md0.z & md0.w & md1.x & md1.y & md1.z & md1.w;
    unsigned long long bl = __ballot(w == 0x01010101u);
    if (lane == 0) sflag[wv] = (bl == ~0ull) ? 1 : 0;
  }
  __syncthreads();
  bool allm = true;
  #pragma unroll
  for (int w = 0; w < 8; ++w) allm = allm && sflag[w];

  if (allm) {
    scan_run<false>(tid, c, g, wv, tb, b0, Ef, xbA, xbB, WlA, WlB,
                    mkl, mkl + 16, MpA, MpB, SpA, SpB, score, out);
  } else {
    scan_run<true>(tid, c, g, wv, tb, b0, Ef, xbA, xbB, WlA, WlB,
                   mkl, mkl + 16, MpA, MpB, SpA, SpB, score, out);
  }
}

extern "C" void kernel_launch(void* const* d_in, const int* in_sizes, int n_in,
                              void* d_out, int out_size, void* d_ws, size_t ws_size,
                              hipStream_t stream) {
  const float* yp = (const float*)d_in[0];
  const float* trans = (const float*)d_in[1];
  const int* ytrue = (const int*)d_in[2];
  float* out = (float*)d_out;

  unsigned short* Efrag = (unsigned short*)d_ws;                 // 128 KB
  unsigned char* masks = (unsigned char*)d_ws + 131072;          // 64 KB
  float* score = (float*)((char*)d_ws + 131072 + 65536);         // 512 B

  prep_E<<<dim3(256), dim3(256), 0, stream>>>(trans, Efrag);
  aux_mask<<<dim3(16384), dim3(256), 0, stream>>>(yp, masks);
  aux_score<<<dim3(128), dim3(64), 0, stream>>>(yp, trans, ytrue, masks, score);
  crf_scan<<<dim3(4), dim3(512), 0, stream>>>(yp, Efrag, masks, score, out);
}

// Round 14
// 297.760 us; speedup vs baseline: 4.3090x; 1.6132x over previous
//
#include <hip/hip_runtime.h>
#include <stdint.h>

#define T_ 512
#define K_ 256
#define NB 16
#define WROW 264   // bf16 W row stride in ushorts
#define L2E 1.4426950408889634f
#define LN2 0.6931471805599453f

typedef __attribute__((ext_vector_type(8))) short short8;
typedef __attribute__((ext_vector_type(4))) float f32x4;

__device__ __forceinline__ float fexp2(float x) {
#if __has_builtin(__builtin_amdgcn_exp2f)
  return __builtin_amdgcn_exp2f(x);
#else
  return exp2f(x);
#endif
}
__device__ __forceinline__ float flog2(float x) {
#if __has_builtin(__builtin_amdgcn_logf)
  return __builtin_amdgcn_logf(x);
#else
  return log2f(x);
#endif
}
__device__ __forceinline__ unsigned int umax_(unsigned int a, unsigned int b) {
  return a > b ? a : b;
}
__device__ __forceinline__ float bits2f(uint32_t u) { return __builtin_bit_cast(float, u); }
__device__ __forceinline__ uint32_t f2bits(float f) { return __builtin_bit_cast(uint32_t, f); }

__device__ __forceinline__ unsigned short f2bf(float f) {
  union { float f; uint32_t u; } v; v.f = f;
  uint32_t r = v.u + 0x7fffu + ((v.u >> 16) & 1u);
  return (unsigned short)(r >> 16);
}
__device__ __forceinline__ uint32_t cvt_pk_bf16(float a, float b) {
  uint32_t d;
  asm("v_cvt_pk_bf16_f32 %0, %1, %2" : "=v"(d) : "v"(a), "v"(b));
  return d;
}

#define BAR() do { \
  asm volatile("s_waitcnt lgkmcnt(0)" ::: "memory"); \
  __builtin_amdgcn_s_barrier(); \
  asm volatile("" ::: "memory"); \
} while (0)

// ---------- fused aux: prep_E + mask + point-score partials ----------
// grid 16384 x 256. Each 64-lane row handles one (b,t) item: mask + psum.
// Blocks 0..255 additionally produce the E fragment table (independent data).

__global__ void aux_fused(const float* __restrict__ yp, const float* __restrict__ trans,
                          const int* __restrict__ ytrue,
                          unsigned short* __restrict__ Efrag,
                          unsigned char* __restrict__ masks,
                          float* __restrict__ psum) {
  int item = blockIdx.x * 4 + (threadIdx.x >> 6);  // b*512 + t
  int lane = threadIdx.x & 63;
  const float4 v = *(const float4*)(yp + (size_t)item * K_ + lane * 4);
  float mn = fminf(fminf(v.x, v.y), fminf(v.z, v.w));
  unsigned long long bl = __ballot(mn > -1000000.0f);
  int m = (bl == ~0ull) ? 1 : 0;
  if (lane == 0) {
    int b = item >> 9, t = item & 511;
    masks[t * 128 + b] = (unsigned char)m;
  }
  // point-score partial: owning lane writes x[y] (masked)
  {
    int y = ytrue[item];  // ytrue is [B][T] flat == item order
    if ((y >> 2) == lane) {
      float xv = (y & 3) == 0 ? v.x : ((y & 3) == 1 ? v.y : ((y & 3) == 2 ? v.z : v.w));
      psum[item] = m ? xv : 0.0f;
    }
  }
  // E fragments (bf16 A-frag layout for mfma_f32_16x16x32_bf16, proven r2..r12)
  if (blockIdx.x < 256) {
    int idx = blockIdx.x * 256 + threadIdx.x;  // 0..65535
    int e = idx & 7;
    int ln = (idx >> 3) & 63;
    int kb = (idx >> 9) & 7;
    int mt = idx >> 12;
    int j = mt * 16 + (ln & 15);
    int k = kb * 32 + ((ln >> 4) << 3) + e;
    Efrag[idx] = f2bf(__expf(trans[k * K_ + j]));
  }
}

// score[b] = sum_t psum[b,t] + trans-score (no yp gathers left)
__global__ void aux_score(const float* __restrict__ psum, const float* __restrict__ trans,
                          const int* __restrict__ ytrue, const unsigned char* __restrict__ masks,
                          float* __restrict__ score) {
  int b = blockIdx.x;
  int lane = threadIdx.x;  // 0..63
  float s = 0.f;
  #pragma unroll
  for (int k = 0; k < 8; ++k) {
    int t = lane + 64 * k;
    s += psum[b * T_ + t];
    if (t >= 1) {
      int y = ytrue[b * T_ + t];
      int ym = ytrue[b * T_ + t - 1];
      int m = masks[t * 128 + b];
      int mm = masks[(t - 1) * 128 + b];
      if (m && mm) s += trans[ym * K_ + y];
    }
  }
  #pragma unroll
  for (int off = 32; off; off >>= 1) s += __shfl_xor(s, off, 64);
  if (lane == 0) score[b] = s;
}

// ---------- scan: r6-exact (8 waves, 2 tiles/wave, 1 BAR/step) ----------

template<int TM4, bool RESC, bool MWR, bool MASKED>
__device__ __forceinline__ void crf_step(
    int t, int c, int g, int wv, const int* tb,
    const short8 (&Ef)[2][8],
    float (&a)[8], float (&exf)[8], int& acc, int& mkc,
    const float* xb, float4 (&XN)[2], float4 (&XI)[2],
    unsigned short (*Wl)[NB * WROW], const unsigned char* mkl, unsigned int* Mpart) {
  BAR();
  if (RESC) {
    unsigned int Mx = Mpart[c];
    #pragma unroll
    for (int w = 1; w < 8; ++w) Mx = umax_(Mx, Mpart[w * NB + c]);
    unsigned int e_ = Mx >> 23;
    float sf = bits2f((254u - e_) << 23);
    if (!MASKED || mkc) acc += 127 - (int)e_;
    #pragma unroll
    for (int j = 0; j < 8; ++j) exf[j] *= sf;
  }
  f32x4 ac0 = {0.f, 0.f, 0.f, 0.f}, ac1 = {0.f, 0.f, 0.f, 0.f};
  {
    const unsigned short* rrow = &Wl[TM4 & 1][c * WROW];
    #pragma unroll
    for (int kb = 0; kb < 8; ++kb) {
      short8 bf = __builtin_bit_cast(short8, *(const uint4*)(&rrow[kb * 32 + g * 8]));
      ac0 = __builtin_amdgcn_mfma_f32_16x16x32_bf16(Ef[0][kb], bf, ac0, 0, 0, 0);
      ac1 = __builtin_amdgcn_mfma_f32_16x16x32_bf16(Ef[1][kb], bf, ac1, 0, 0, 0);
    }
  }
  if (MASKED) {
    #pragma unroll
    for (int i = 0; i < 4; ++i) { float an = ac0[i] * exf[i];     a[i]     = mkc ? an : a[i]; }
    #pragma unroll
    for (int i = 0; i < 4; ++i) { float an = ac1[i] * exf[4 + i]; a[4 + i] = mkc ? an : a[4 + i]; }
  } else {
    #pragma unroll
    for (int i = 0; i < 4; ++i) a[i]     = ac0[i] * exf[i];
    #pragma unroll
    for (int i = 0; i < 4; ++i) a[4 + i] = ac1[i] * exf[4 + i];
  }
  {
    unsigned short* wrow = &Wl[(TM4 + 1) & 1][c * WROW];
    #pragma unroll
    for (int m = 0; m < 2; ++m) {
      uint2 pp;
      pp.x = cvt_pk_bf16(a[4 * m + 0], a[4 * m + 1]);
      pp.y = cvt_pk_bf16(a[4 * m + 2], a[4 * m + 3]);
      *(uint2*)(&wrow[tb[m]]) = pp;
    }
  }
  if (MWR) {
    unsigned int pm = f2bits(a[0]);
    #pragma unroll
    for (int j = 1; j < 8; ++j) pm = umax_(pm, f2bits(a[j]));
    pm = umax_(pm, (unsigned int)__shfl_xor((int)pm, 16, 64));
    pm = umax_(pm, (unsigned int)__shfl_xor((int)pm, 32, 64));
    if (g == 0) Mpart[wv * NB + c] = pm;
  }
  #pragma unroll
  for (int m = 0; m < 2; ++m) {
    exf[4 * m + 0] = fexp2(XN[m].x * L2E);
    exf[4 * m + 1] = fexp2(XN[m].y * L2E);
    exf[4 * m + 2] = fexp2(XN[m].z * L2E);
    exf[4 * m + 3] = fexp2(XN[m].w * L2E);
  }
  if (MASKED) mkc = mkl[(t + 1 < T_ ? t + 1 : 0) * NB + c];
  {
    int tt = t + 4;
    tt = tt > (T_ - 1) ? (T_ - 1) : tt;
    #pragma unroll
    for (int m = 0; m < 2; ++m)
      XI[m] = *(const float4*)(xb + (size_t)tt * K_ + tb[m]);
  }
}

template<bool MASKED>
__device__ __forceinline__ void scan_run(
    int tid, int c, int g, int wv, const int* tb, int b0,
    const short8 (&Ef)[2][8], const float* xb,
    float4 (&xinit)[2], float4 (&X0q)[2], float4 (&X1q)[2],
    float4 (&X2q)[2], float4 (&X3q)[2],
    unsigned short (*Wl)[NB * WROW], const unsigned char* mkl,
    unsigned int* Mpart, float* Spart,
    const float* __restrict__ score, float* __restrict__ out) {
  float a[8], exf[8];
  int acc = 0;
  int mkc = 0;
  {
    int mk0 = MASKED ? mkl[c] : 1;
    #pragma unroll
    for (int m = 0; m < 2; ++m) {
      float e0 = fexp2(xinit[m].x * L2E);
      float e1 = fexp2(xinit[m].y * L2E);
      float e2 = fexp2(xinit[m].z * L2E);
      float e3 = fexp2(xinit[m].w * L2E);
      a[4 * m + 0] = (MASKED && !mk0) ? 1.0f : e0;
      a[4 * m + 1] = (MASKED && !mk0) ? 1.0f : e1;
      a[4 * m + 2] = (MASKED && !mk0) ? 1.0f : e2;
      a[4 * m + 3] = (MASKED && !mk0) ? 1.0f : e3;
    }
  }
  {
    unsigned short* wrow = &Wl[1][c * WROW];
    #pragma unroll
    for (int m = 0; m < 2; ++m) {
      uint2 pp;
      pp.x = cvt_pk_bf16(a[4 * m + 0], a[4 * m + 1]);
      pp.y = cvt_pk_bf16(a[4 * m + 2], a[4 * m + 3]);
      *(uint2*)(&wrow[tb[m]]) = pp;
    }
  }
  #pragma unroll
  for (int m = 0; m < 2; ++m) {
    exf[4 * m + 0] = fexp2(X1q[m].x * L2E);
    exf[4 * m + 1] = fexp2(X1q[m].y * L2E);
    exf[4 * m + 2] = fexp2(X1q[m].z * L2E);
    exf[4 * m + 3] = fexp2(X1q[m].w * L2E);
  }
  if (MASKED) mkc = mkl[NB + c];

  crf_step<1, false, false, MASKED>(1, c, g, wv, tb, Ef, a, exf, acc, mkc, xb, X2q, X1q, Wl, mkl, Mpart);
  crf_step<2, false, false, MASKED>(2, c, g, wv, tb, Ef, a, exf, acc, mkc, xb, X3q, X2q, Wl, mkl, Mpart);
  crf_step<3, false, true , MASKED>(3, c, g, wv, tb, Ef, a, exf, acc, mkc, xb, X0q, X3q, Wl, mkl, Mpart);

  #pragma unroll 1
  for (int t0 = 4; t0 < T_; t0 += 4) {
    crf_step<0, true , false, MASKED>(t0,     c, g, wv, tb, Ef, a, exf, acc, mkc, xb, X1q, X0q, Wl, mkl, Mpart);
    crf_step<1, false, false, MASKED>(t0 + 1, c, g, wv, tb, Ef, a, exf, acc, mkc, xb, X2q, X1q, Wl, mkl, Mpart);
    crf_step<2, false, false, MASKED>(t0 + 2, c, g, wv, tb, Ef, a, exf, acc, mkc, xb, X3q, X2q, Wl, mkl, Mpart);
    crf_step<3, false, true , MASKED>(t0 + 3, c, g, wv, tb, Ef, a, exf, acc, mkc, xb, X0q, X3q, Wl, mkl, Mpart);
  }

  __syncthreads();
  {
    float ssum = 0.f;
    #pragma unroll
    for (int j = 0; j < 8; ++j) ssum += a[j];
    ssum += __shfl_xor(ssum, 16, 64);
    ssum += __shfl_xor(ssum, 32, 64);
    if (g == 0) Spart[wv * NB + c] = ssum;
  }
  __syncthreads();
  if (tid < NB) {
    float S = 0.f;
    #pragma unroll
    for (int w = 0; w < 8; ++w) S += Spart[w * NB + tid];
    out[b0 + tid] = LN2 * (flog2(S) - (float)acc) - score[b0 + tid];
  }
}

__global__ __launch_bounds__(512, 1) void crf_scan(
    const float* __restrict__ yp, const unsigned short* __restrict__ Efrag,
    const unsigned char* __restrict__ masks, const float* __restrict__ score,
    float* __restrict__ out) {
  const int b0 = blockIdx.x * NB;
  const int tid = threadIdx.x;
  const int wv = tid >> 6, lane = tid & 63;
  const int c = lane & 15;
  const int g = lane >> 4;

  __shared__ unsigned short Wl[2][NB * WROW];
  __shared__ unsigned char mkl[T_ * NB];
  __shared__ unsigned int Mpart[8 * NB];
  __shared__ float Spart[8 * NB];
  __shared__ int sflag[8];

  short8 Ef[2][8];
  {
    const uint4* ep = (const uint4*)Efrag;
    #pragma unroll
    for (int m = 0; m < 2; ++m)
      #pragma unroll
      for (int kb = 0; kb < 8; ++kb)
        Ef[m][kb] = __builtin_bit_cast(short8, ep[((wv * 2 + m) * 8 + kb) * 64 + lane]);
  }

  uint4 md0;
  {
    uint4* dst = (uint4*)mkl;
    md0 = *(const uint4*)(masks + tid * 128 + b0);
    dst[tid] = md0;
  }

  const float* xb = yp + (size_t)(b0 + c) * T_ * K_;
  int tb[2];
  #pragma unroll
  for (int m = 0; m < 2; ++m) tb[m] = wv * 32 + m * 16 + g * 4;

  float4 xinit[2], X0q[2], X1q[2], X2q[2], X3q[2];
  #pragma unroll
  for (int m = 0; m < 2; ++m) xinit[m] = *(const float4*)(xb + tb[m]);
  #pragma unroll
  for (int m = 0; m < 2; ++m) X1q[m] = *(const float4*)(xb + 1 * K_ + tb[m]);
  #pragma unroll
  for (int m = 0; m < 2; ++m) X2q[m] = *(const float4*)(xb + 2 * K_ + tb[m]);
  #pragma unroll
  for (int m = 0; m < 2; ++m) X3q[m] = *(const float4*)(xb + 3 * K_ + tb[m]);
  #pragma unroll
  for (int m = 0; m < 2; ++m) X0q[m] = *(const float4*)(xb + 4 * K_ + tb[m]);

  {
    uint32_t w = md0.x & md0.y & md0.z & md0.w;
    unsigned long long bl = __ballot(w == 0x01010101u);
    if (lane == 0) sflag[wv] = (bl == ~0ull) ? 1 : 0;
  }
  __syncthreads();
  bool allm = true;
  #pragma unroll
  for (int w = 0; w < 8; ++w) allm = allm && sflag[w];

  if (allm) {
    scan_run<false>(tid, c, g, wv, tb, b0, Ef, xb, xinit, X0q, X1q, X2q, X3q,
                    Wl, mkl, Mpart, Spart, score, out);
  } else {
    scan_run<true>(tid, c, g, wv, tb, b0, Ef, xb, xinit, X0q, X1q, X2q, X3q,
                   Wl, mkl, Mpart, Spart, score, out);
  }
}

extern "C" void kernel_launch(void* const* d_in, const int* in_sizes, int n_in,
                              void* d_out, int out_size, void* d_ws, size_t ws_size,
                              hipStream_t stream) {
  const float* yp = (const float*)d_in[0];
  const float* trans = (const float*)d_in[1];
  const int* ytrue = (const int*)d_in[2];
  float* out = (float*)d_out;

  unsigned short* Efrag = (unsigned short*)d_ws;                  // 128 KB @ 0
  unsigned char* masks = (unsigned char*)d_ws + 131072;           // 64 KB
  float* psum = (float*)((char*)d_ws + 196608);                   // 256 KB
  float* score = (float*)((char*)d_ws + 458752);                  // 512 B

  aux_fused<<<dim3(16384), dim3(256), 0, stream>>>(yp, trans, ytrue, Efrag, masks, psum);
  aux_score<<<dim3(128), dim3(64), 0, stream>>>(psum, trans, ytrue, masks, score);
  crf_scan<<<dim3(8), dim3(512), 0, stream>>>(yp, Efrag, masks, score, out);
}